// Round 1
// baseline (247.840 us; speedup 1.0000x reference)
//
#include <hip/hip_runtime.h>
#include <hip/hip_bf16.h>

#define D_FEAT 64
#define OVF_CAP 65536
#define EB 4096              // edges per block in the multisplit
#define NBMAX 1024           // max coarse buckets (n <= 256K)
#define NSLICE 4             // feature slices (16 feats = 32B bf16 = 64B fp32 each)

typedef unsigned int uint32;

__device__ inline float blo(uint32 u) { return __uint_as_float(u << 16); }
__device__ inline float bhi(uint32 u) { return __uint_as_float(u & 0xffff0000u); }
__device__ inline float dinv(int d) { return (d > 0) ? rsqrtf((float)d) : 0.0f; }

// ---- phase 1: per-block LDS histogram over coarse buckets + fused bf16 cast ----
// xb layout is SLICE-MAJOR: xbs[slice][node][8 x uint32]  (slice = 16 features)
__global__ __launch_bounds__(256) void k_hist(const int* __restrict__ col,
                                              int* __restrict__ histT,
                                              const float2* __restrict__ x2,
                                              uint32* __restrict__ xb,
                                              int nhalf, int E, int B, int nb,
                                              int n) {
    __shared__ int h[NBMAX];
    for (int i = threadIdx.x; i < nb; i += 256) h[i] = 0;
    __syncthreads();
    const int b = blockIdx.x;
    const int s = b * EB;
    const int e = (s + EB < E) ? s + EB : E;
    for (int i = s + threadIdx.x; i < e; i += 256)
        atomicAdd(&h[col[i] >> 8], 1);
    __syncthreads();
    for (int k = threadIdx.x; k < nb; k += 256)
        histT[(size_t)k * B + b] = h[k];            // bucket-major for the scan
    // fused bf16 cast -> slice-major layout (bandwidth work, hides behind atomics)
    const int t = b * 256 + threadIdx.x;
    const int stride = B * 256;
    for (int j = t; j < nhalf; j += stride) {
        float2 v = x2[j];
        __hip_bfloat16 bx = __float2bfloat16(v.x);
        __hip_bfloat16 by = __float2bfloat16(v.y);
        uint32 ux = *reinterpret_cast<unsigned short*>(&bx);
        uint32 uy = *reinterpret_cast<unsigned short*>(&by);
        uint32 u = ux | (uy << 16);
        int node = j >> 5;                 // 32 float-pairs per node
        int p = j & 31;
        int slice = p >> 3;                // 8 pairs per slice
        int fp = p & 7;
        xb[((size_t)slice * n + node) * 8 + fp] = u;
    }
}

// ---- phase 2a: per-bucket exclusive scan over blocks (one block per bucket) ----
__global__ __launch_bounds__(512) void k_colscan(int* __restrict__ histT,
                                                 int* __restrict__ total, int B) {
    __shared__ int sh[512];
    const int k = blockIdx.x;
    int v = (threadIdx.x < B) ? histT[(size_t)k * B + threadIdx.x] : 0;
    sh[threadIdx.x] = v;
    __syncthreads();
    for (int off = 1; off < 512; off <<= 1) {
        int t = (threadIdx.x >= off) ? sh[threadIdx.x - off] : 0;
        __syncthreads();
        sh[threadIdx.x] += t;
        __syncthreads();
    }
    int incl = sh[threadIdx.x];
    if (threadIdx.x < B) histT[(size_t)k * B + threadIdx.x] = incl - v;  // exclusive
    if (threadIdx.x == 511) total[k] = incl;
}

// ---- phase 2b: scan bucket totals -> bstart (one block) ----
__global__ __launch_bounds__(1024) void k_tinyscan(const int* __restrict__ total,
                                                   int* __restrict__ bstart, int nb) {
    __shared__ int sh[1024];
    int v = (threadIdx.x < nb) ? total[threadIdx.x] : 0;
    sh[threadIdx.x] = v;
    __syncthreads();
    for (int off = 1; off < 1024; off <<= 1) {
        int t = (threadIdx.x >= off) ? sh[threadIdx.x - off] : 0;
        __syncthreads();
        sh[threadIdx.x] += t;
        __syncthreads();
    }
    if (threadIdx.x < nb) bstart[threadIdx.x] = sh[threadIdx.x] - v;
    if (threadIdx.x == nb - 1) bstart[nb] = sh[threadIdx.x];
}

// ---- phase 3: place edges into bucket segments via LDS cursors (no global atomics) ----
__global__ __launch_bounds__(256) void k_scat3(const int* __restrict__ row,
                                               const int* __restrict__ col,
                                               const int* __restrict__ histT,
                                               const int* __restrict__ bstart,
                                               uint32* __restrict__ binned,
                                               int E, int B, int nb) {
    __shared__ int cur[NBMAX];
    const int b = blockIdx.x;
    for (int k = threadIdx.x; k < nb; k += 256)
        cur[k] = bstart[k] + histT[(size_t)k * B + b];
    __syncthreads();
    const int s = b * EB;
    const int e = (s + EB < E) ? s + EB : E;
    for (int i = s + threadIdx.x; i < e; i += 256) {
        int c = col[i];
        uint32 r = (uint32)row[i];
        int pos = atomicAdd(&cur[c >> 8], 1);       // LDS atomic
        binned[pos] = (r << 8) | (uint32)(c & 255);
    }
}

// ---- phase 4: per-bucket LDS ranks -> padded slots; fused deg output ----
__global__ __launch_bounds__(1024) void k_build(const int* __restrict__ bstart,
                                                const uint32* __restrict__ binned,
                                                int* __restrict__ slots,
                                                int* __restrict__ deg,
                                                int2* __restrict__ ovf,
                                                int* __restrict__ ovf_cnt,
                                                int n, int C) {
    __shared__ int cnt[256];
    const int k = blockIdx.x;
    if (threadIdx.x < 256) cnt[threadIdx.x] = 0;
    __syncthreads();
    const int s = bstart[k], e = bstart[k + 1];
    const int base = k << 8;
    for (int i = s + threadIdx.x; i < e; i += 1024) {
        uint32 pk = binned[i];
        int cl = (int)(pk & 255);
        int r  = (int)(pk >> 8);
        int rk = atomicAdd(&cnt[cl], 1);            // LDS atomic
        int c  = base + cl;
        if (rk < C) {
            slots[(size_t)c * C + rk] = r;          // block-private 32KB window
        } else {
            int o = atomicAdd(ovf_cnt, 1);
            if (o < OVF_CAP) ovf[o] = make_int2(r, c);
        }
    }
    __syncthreads();
    int i = base + threadIdx.x;
    if (threadIdx.x < 256 && i < n) deg[i] = cnt[threadIdx.x];
}

// ---- gather: one wave per (node, slice); 16 edges in parallel per iteration ----
// slice = blockIdx & 3 -> with round-robin XCD dispatch, each slice's 3.2MB xb
// shard stays resident in the L2 of the two XCDs that serve it.
__global__ __launch_bounds__(256) void k_gather_s(const uint2* __restrict__ xbs,
                                                  const float4* __restrict__ x4,
                                                  const int* __restrict__ deg,
                                                  const int* __restrict__ slots,
                                                  const float* __restrict__ alpha_p,
                                                  const float* __restrict__ rs_p,
                                                  float4* __restrict__ out4,
                                                  int n, int C) {
    const int slice = blockIdx.x & (NSLICE - 1);
    const int chunk = blockIdx.x >> 2;
    const int wv = threadIdx.x >> 6;             // 0..3 (4 waves/block)
    const int node = chunk * 4 + wv;
    if (node >= n) return;
    const int lane = threadIdx.x & 63;
    const int q = lane >> 2;                     // edge group 0..15
    const int l = lane & 3;                      // feature quad 0..3 (4 bf16 = uint2)
    int d = deg[node];
    int e = (d < C) ? d : C;
    const int* sl = slots + (size_t)node * C;
    // hoist the residual load: hide its HBM latency under the edge loop
    float4 xr = make_float4(0.f, 0.f, 0.f, 0.f);
    if (q == 0) xr = x4[(size_t)node * 16 + slice * 4 + l];
    float ax = 0.f, ay = 0.f, az = 0.f, aw = 0.f;
    const size_t sb = (size_t)slice * n;         // slice base (rows)
    int k = 0;
    for (; k + 16 <= e; k += 16) {
        int s0 = sl[k + q];
        float w0 = dinv(deg[s0]);
        uint2 p0 = xbs[(sb + s0) * 4 + l];
        ax = fmaf(w0, blo(p0.x), ax); ay = fmaf(w0, bhi(p0.x), ay);
        az = fmaf(w0, blo(p0.y), az); aw = fmaf(w0, bhi(p0.y), aw);
    }
    if (k < e) {                                  // tail: at most 15 edges
        int kk = k + q;
        if (kk < e) {
            int s0 = sl[kk];
            float w0 = dinv(deg[s0]);
            uint2 p0 = xbs[(sb + s0) * 4 + l];
            ax = fmaf(w0, blo(p0.x), ax); ay = fmaf(w0, bhi(p0.x), ay);
            az = fmaf(w0, blo(p0.y), az); aw = fmaf(w0, bhi(p0.y), aw);
        }
    }
    // reduce across the 16 edge groups (stride-4 lanes keep the same feature quad)
    ax += __shfl_down(ax, 32, 64); ay += __shfl_down(ay, 32, 64);
    az += __shfl_down(az, 32, 64); aw += __shfl_down(aw, 32, 64);
    ax += __shfl_down(ax, 16, 64); ay += __shfl_down(ay, 16, 64);
    az += __shfl_down(az, 16, 64); aw += __shfl_down(aw, 16, 64);
    ax += __shfl_down(ax,  8, 64); ay += __shfl_down(ay,  8, 64);
    az += __shfl_down(az,  8, 64); aw += __shfl_down(aw,  8, 64);
    ax += __shfl_down(ax,  4, 64); ay += __shfl_down(ay,  4, 64);
    az += __shfl_down(az,  4, 64); aw += __shfl_down(aw,  4, 64);
    if (q == 0) {
        float adw = (*alpha_p) * dinv(d);
        float rs  = *rs_p;
        float4 o;
        o.x = fmaf(adw, ax, rs * xr.x);
        o.y = fmaf(adw, ay, rs * xr.y);
        o.z = fmaf(adw, az, rs * xr.z);
        o.w = fmaf(adw, aw, rs * xr.w);
        out4[(size_t)node * 16 + slice * 4 + l] = o;
    }
}

// ---- overflow fix-up (rare): fp32 exact ----
__global__ void k_ovf(const int2* __restrict__ ovf, const int* __restrict__ cnt_p,
                      const float* __restrict__ x, const int* __restrict__ deg,
                      const float* __restrict__ alpha_p, float* __restrict__ out) {
    int cnt = *cnt_p;
    if (cnt > OVF_CAP) cnt = OVF_CAP;
    if (cnt <= 0) return;
    float a = *alpha_p;
    long long total = (long long)cnt * 64;
    long long stride = (long long)gridDim.x * blockDim.x;
    for (long long idx = blockIdx.x * (long long)blockDim.x + threadIdx.x;
         idx < total; idx += stride) {
        int e = (int)(idx >> 6);
        int f = (int)(idx & 63);
        int2 rc = ovf[e];
        float w = a * dinv(deg[rc.x]) * dinv(deg[rc.y]);
        atomicAdd(&out[(size_t)rc.y * D_FEAT + f], w * x[(size_t)rc.x * D_FEAT + f]);
    }
}

// ================= fallback: round-8 direct padded-CSR build =================
__global__ void k_prep(const float2* __restrict__ x2, uint32* __restrict__ xb,
                       const int* __restrict__ row, const int* __restrict__ col,
                       int* __restrict__ deg, int* __restrict__ slots,
                       int2* __restrict__ ovf, int* __restrict__ ovf_cnt,
                       int nhalf, int E, int C, int n) {
    int t = blockIdx.x * blockDim.x + threadIdx.x;
    if (t < E) {
        int c = col[t];
        int r = row[t];
        int rk = atomicAdd(&deg[c], 1);
        if (rk < C) {
            slots[(size_t)c * C + rk] = r;
        } else {
            int o = atomicAdd(ovf_cnt, 1);
            if (o < OVF_CAP) ovf[o] = make_int2(r, c);
        }
    }
    const int stride = gridDim.x * blockDim.x;
    for (int j = t; j < nhalf; j += stride) {
        float2 v = x2[j];
        __hip_bfloat16 bx = __float2bfloat16(v.x);
        __hip_bfloat16 by = __float2bfloat16(v.y);
        uint32 ux = *reinterpret_cast<unsigned short*>(&bx);
        uint32 uy = *reinterpret_cast<unsigned short*>(&by);
        uint32 u = ux | (uy << 16);
        int node = j >> 5;
        int p = j & 31;
        int slice = p >> 3;
        int fp = p & 7;
        xb[((size_t)slice * n + node) * 8 + fp] = u;
    }
}

static inline char* align_up(char* p, size_t a) {
    return (char*)(((uintptr_t)p + (a - 1)) & ~(uintptr_t)(a - 1));
}

extern "C" void kernel_launch(void* const* d_in, const int* in_sizes, int n_in,
                              void* d_out, int out_size, void* d_ws, size_t ws_size,
                              hipStream_t stream) {
    const float* x         = (const float*)d_in[0];
    const float* alpha     = (const float*)d_in[1];
    const float* res_scale = (const float*)d_in[2];
    const int*   ei        = (const int*)d_in[3];

    const int n = in_sizes[0] / D_FEAT;      // 100000
    const int E = in_sizes[3] / 2;           // 1600000
    const int* row = ei;                     // sources
    const int* col = ei + E;                 // targets

    float* out = (float*)d_out;
    const int nhalf = n * (D_FEAT / 2);
    const int nb = (n + 255) >> 8;           // coarse buckets (256 nodes each)
    const int B  = (E + EB - 1) / EB;        // multisplit blocks

    // ---------- multisplit layout ----------
    {
        char* p = (char*)d_ws;
        int*    deg     = (int*)p;            p += (size_t)n * 4;
        int*    ovf_cnt = (int*)p;            p += 4;
        int2*   ovf     = (int2*)p;           p += (size_t)OVF_CAP * 8;
        int*    histT   = (int*)p;            p += (size_t)nb * B * 4;
        int*    total   = (int*)p;            p += (size_t)nb * 4;
        int*    bstart  = (int*)p;            p += (size_t)(nb + 1) * 4;
        p = align_up(p, 16);
        uint32* xb      = (uint32*)p;         p += (size_t)n * 128;
        uint32* binned  = (uint32*)p;         p += (size_t)E * 4;
        int*    slots   = (int*)p;
        const size_t fixed = (size_t)(p - (char*)d_ws);

        int C = 0;
        if (ws_size > fixed) {
            size_t c_avail = (ws_size - fixed) / ((size_t)n * 4);
            C = (c_avail > 32) ? 32 : (int)c_avail;
        }
        const bool ok = (C >= 16) && (nb <= NBMAX) && (B <= 512) &&
                        (n <= (NBMAX << 8));
        if (ok) {
            hipMemsetAsync(ovf_cnt, 0, 4, stream);
            k_hist    <<<B, 256, 0, stream>>>(col, histT, (const float2*)x, xb,
                                              nhalf, E, B, nb, n);
            k_colscan <<<nb, 512, 0, stream>>>(histT, total, B);
            k_tinyscan<<<1, 1024, 0, stream>>>(total, bstart, nb);
            k_scat3   <<<B, 256, 0, stream>>>(row, col, histT, bstart, binned,
                                              E, B, nb);
            k_build   <<<nb, 1024, 0, stream>>>(bstart, binned, slots, deg,
                                                ovf, ovf_cnt, n, C);
            const int gblocks = ((n + 3) >> 2) * NSLICE;  // 4 waves/block, 1 slice/block
            k_gather_s<<<gblocks, 256, 0, stream>>>((const uint2*)xb, (const float4*)x,
                                                    deg, slots, alpha, res_scale,
                                                    (float4*)out, n, C);
            k_ovf<<<64, 256, 0, stream>>>(ovf, ovf_cnt, x, deg, alpha, out);
            return;
        }
    }

    // ---------- fallback: round-8 direct padded CSR ----------
    {
        char* p = (char*)d_ws;
        int*    deg     = (int*)p;            p += (size_t)n * 4;
        int*    ovf_cnt = (int*)p;            p += 4;
        int2*   ovf     = (int2*)p;           p += (size_t)OVF_CAP * 8;
        p = align_up(p, 16);
        uint32* xb      = (uint32*)p;         p += (size_t)n * 128;
        int*    slots   = (int*)p;
        const size_t fixed = (size_t)(p - (char*)d_ws);
        int C = 0;
        if (ws_size > fixed) {
            size_t c_avail = (ws_size - fixed) / ((size_t)n * 4);
            C = (c_avail > 32) ? 32 : (int)c_avail;
        }
        if (C < 1) return;  // ws too small for anything sane
        hipMemsetAsync(deg, 0, (size_t)n * 4 + 4, stream);
        k_prep<<<(E + 255) / 256, 256, 0, stream>>>(
            (const float2*)x, xb, row, col, deg, slots, ovf, ovf_cnt,
            nhalf, E, C, n);
        const int gblocks = ((n + 3) >> 2) * NSLICE;
        k_gather_s<<<gblocks, 256, 0, stream>>>((const uint2*)xb, (const float4*)x,
                                                deg, slots, alpha, res_scale,
                                                (float4*)out, n, C);
        k_ovf<<<64, 256, 0, stream>>>(ovf, ovf_cnt, x, deg, alpha, out);
    }
}